// Round 2
// 334.528 us; speedup vs baseline: 1.0348x; 1.0348x over previous
//
#include <hip/hip_runtime.h>

#define NB 4
#define NC 64
#define NH 256
#define NW 256
#define PLANE ((long)NB * NC * NH * NW)   // 16.78M elements per direction
#define HW    ((long)NH * NW)

// V2b: all-streaming fused kernel, zero LDS, zero barriers (hardened resubmit).
//
// Vertical (up/down): thread per float2 column pair, 8-deep load batches.
//   Blocks [0,128)=up, [128,256)=down.
//
// Horizontal (right/left): FUSED. One wave owns one full W-row in registers
//   (lane l holds float4 = elems 4l..4l+3, coalesced 1KB/wave load) and
//   produces BOTH direction outputs from a single read of x.
//   h' = relu(w*h + b + x) composes as f(h) = max(c, m*h + d):
//     (f2∘f1) = (max(c2, m2*c1 + d2), m2*m1, m2*d1 + d2)  [valid since m>=0;
//     here w == 1.0 exactly]. Lane with the boundary element has m == 0
//     exactly, so every inclusive composite is a constant: h = max(c, d).
//   6-step shfl Hillis-Steele scan distributes h_in; each lane then replays
//   its 4 elements with the REFERENCE association (w*h + b + x) so only h_in
//   carries scan-reassociation rounding.
__global__ __launch_bounds__(256) void irnn_fused(
    const float* __restrict__ x,
    const float* __restrict__ w_up,    const float* __restrict__ b_up,
    const float* __restrict__ w_right, const float* __restrict__ b_right,
    const float* __restrict__ w_down,  const float* __restrict__ b_down,
    const float* __restrict__ w_left,  const float* __restrict__ b_left,
    float* __restrict__ out)
{
    const int t   = threadIdx.x;
    const int blk = blockIdx.x;

    if (blk < 256) {
        // ---------------- vertical scans (float2 per thread) ----------------
        const bool up  = blk < 128;
        const int  tid = (blk & 127) * 256 + t;      // 0..32767 f2-column id
        const int  w2  = (tid & 127) << 1;           // 0,2,..,254
        const int  bc  = tid >> 7;                   // 0..255
        const int  c   = bc & (NC - 1);
        const long base = (long)bc * HW + w2;
        const float wc = up ? w_up[c] : w_down[c];
        const float bb = up ? b_up[c] : b_down[c];
        float* o = out + (up ? 0L : 2L) * PLANE;
        const long stp = up ? -(long)NW : (long)NW;
        long idx = up ? base + (long)(NH - 1) * NW : base;

        float2 h = *(const float2*)(x + idx);        // boundary row = raw input
        *(float2*)(o + idx) = h;
        for (int batch = 0; batch < 31; ++batch) {
            float2 v[8];
            #pragma unroll
            for (int k = 0; k < 8; ++k)
                v[k] = *(const float2*)(x + idx + (long)(k + 1) * stp);
            #pragma unroll
            for (int k = 0; k < 8; ++k) {
                h.x = fmaxf(wc * h.x + bb + v[k].x, 0.0f);
                h.y = fmaxf(wc * h.y + bb + v[k].y, 0.0f);
                *(float2*)(o + idx + (long)(k + 1) * stp) = h;
            }
            idx += 8L * stp;
        }
        float2 v[7];
        #pragma unroll
        for (int k = 0; k < 7; ++k)
            v[k] = *(const float2*)(x + idx + (long)(k + 1) * stp);
        #pragma unroll
        for (int k = 0; k < 7; ++k) {
            h.x = fmaxf(wc * h.x + bb + v[k].x, 0.0f);
            h.y = fmaxf(wc * h.y + bb + v[k].y, 0.0f);
            *(float2*)(o + idx + (long)(k + 1) * stp) = h;
        }
    } else {
        // ------------- horizontal scans (fused right+left, wave/row) -------------
        const int lane = t & 63;
        const int wv   = (blk - 256) * 4 + (t >> 6); // 0..16383
        const int bc   = wv >> 6;                    // 64 waves per (b,c) slab
        const int c    = bc & (NC - 1);
        const int h0   = (wv & 63) * 4;              // 4 rows per wave
        const float wr = w_right[c], br = b_right[c];
        const float wl = w_left[c],  bl = b_left[c];
        float* oR = out + 1L * PLANE;
        float* oL = out + 3L * PLANE;

        long rowb = (long)bc * HW + (long)h0 * NW;
        float4 v = *(const float4*)(x + rowb + lane * 4);

        #pragma unroll
        for (int rr = 0; rr < 4; ++rr) {
            float4 vn = v;
            if (rr < 3) vn = *(const float4*)(x + rowb + NW + lane * 4); // prefetch

            float cc, mm, dd;
            float4 r;

            // ---------------- RIGHT (scan toward +w) ----------------
            if (lane == 0) {
                float h = v.x;                      r.x = h;   // w=0: raw input
                h = fmaxf(wr * h + br + v.y, 0.0f); r.y = h;
                h = fmaxf(wr * h + br + v.z, 0.0f); r.z = h;
                h = fmaxf(wr * h + br + v.w, 0.0f); r.w = h;
                cc = h; mm = 0.0f; dd = h;          // constant function: m exactly 0
            } else {
                cc = 0.0f; mm = wr; dd = br + v.x;
                float a;
                a = br + v.y; cc = fmaxf(0.0f, wr * cc + a); dd = wr * dd + a; mm *= wr;
                a = br + v.z; cc = fmaxf(0.0f, wr * cc + a); dd = wr * dd + a; mm *= wr;
                a = br + v.w; cc = fmaxf(0.0f, wr * cc + a); dd = wr * dd + a; mm *= wr;
            }
            #pragma unroll
            for (int off = 1; off < 64; off <<= 1) {
                float pc = __shfl_up(cc, off, 64);
                float pm = __shfl_up(mm, off, 64);
                float pd = __shfl_up(dd, off, 64);
                if (lane >= off) {                  // mine AFTER partner: mine∘partner
                    cc = fmaxf(cc, mm * pc + dd);
                    dd = mm * pd + dd;
                    mm = mm * pm;
                }
            }
            {
                float pc = __shfl_up(cc, 1, 64);
                float pd = __shfl_up(dd, 1, 64);
                if (lane > 0) {
                    float h = fmaxf(pc, pd);        // neighbor's m == 0 exactly
                    h = fmaxf(wr * h + br + v.x, 0.0f); r.x = h;
                    h = fmaxf(wr * h + br + v.y, 0.0f); r.y = h;
                    h = fmaxf(wr * h + br + v.z, 0.0f); r.z = h;
                    h = fmaxf(wr * h + br + v.w, 0.0f); r.w = h;
                }
            }
            *(float4*)(oR + rowb + lane * 4) = r;

            // ---------------- LEFT (scan toward -w) ----------------
            if (lane == 63) {
                float h = v.w;                      r.w = h;   // w=255: raw input
                h = fmaxf(wl * h + bl + v.z, 0.0f); r.z = h;
                h = fmaxf(wl * h + bl + v.y, 0.0f); r.y = h;
                h = fmaxf(wl * h + bl + v.x, 0.0f); r.x = h;
                cc = h; mm = 0.0f; dd = h;
            } else {
                cc = 0.0f; mm = wl; dd = bl + v.w;
                float a;
                a = bl + v.z; cc = fmaxf(0.0f, wl * cc + a); dd = wl * dd + a; mm *= wl;
                a = bl + v.y; cc = fmaxf(0.0f, wl * cc + a); dd = wl * dd + a; mm *= wl;
                a = bl + v.x; cc = fmaxf(0.0f, wl * cc + a); dd = wl * dd + a; mm *= wl;
            }
            #pragma unroll
            for (int off = 1; off < 64; off <<= 1) {
                float pc = __shfl_down(cc, off, 64);
                float pm = __shfl_down(mm, off, 64);
                float pd = __shfl_down(dd, off, 64);
                if (lane + off < 64) {
                    cc = fmaxf(cc, mm * pc + dd);
                    dd = mm * pd + dd;
                    mm = mm * pm;
                }
            }
            {
                float pc = __shfl_down(cc, 1, 64);
                float pd = __shfl_down(dd, 1, 64);
                if (lane < 63) {
                    float h = fmaxf(pc, pd);
                    h = fmaxf(wl * h + bl + v.w, 0.0f); r.w = h;
                    h = fmaxf(wl * h + bl + v.z, 0.0f); r.z = h;
                    h = fmaxf(wl * h + bl + v.y, 0.0f); r.y = h;
                    h = fmaxf(wl * h + bl + v.x, 0.0f); r.x = h;
                }
            }
            *(float4*)(oL + rowb + lane * 4) = r;

            rowb += NW;
            v = vn;
        }
    }
}

extern "C" void kernel_launch(void* const* d_in, const int* in_sizes, int n_in,
                              void* d_out, int out_size, void* d_ws, size_t ws_size,
                              hipStream_t stream) {
    const float* x       = (const float*)d_in[0];
    const float* w_up    = (const float*)d_in[1];
    const float* w_right = (const float*)d_in[2];
    const float* w_down  = (const float*)d_in[3];
    const float* w_left  = (const float*)d_in[4];
    const float* b_up    = (const float*)d_in[5];
    const float* b_right = (const float*)d_in[6];
    const float* b_down  = (const float*)d_in[7];
    const float* b_left  = (const float*)d_in[8];
    float* out = (float*)d_out;

    // [0,256): vertical (128 up + 128 down, float2 columns)
    // [256,4352): horizontal fused right+left (4096 blocks x 4 waves x 4 rows)
    dim3 grid(256 + 4096);
    irnn_fused<<<grid, 256, 0, stream>>>(
        x, w_up, b_up, w_right, b_right, w_down, b_down, w_left, b_left, out);
}

// Round 4
// 329.807 us; speedup vs baseline: 1.0496x; 1.0143x over previous
//
#include <hip/hip_runtime.h>

#define NB 4
#define NC 64
#define NH 256
#define NW 256
#define PLANE ((long)NB * NC * NH * NW)   // 16.78M elements per direction
#define HW    ((long)NH * NW)

// Native clang vector types: __builtin_nontemporal_store requires these
// (HIP_vector_type float2/float4 are structs and are rejected).
typedef float vf2 __attribute__((ext_vector_type(2)));
typedef float vf4 __attribute__((ext_vector_type(4)));

// V3b: V2's shfl-scan structure + cache-residency optimizations.
//  - All output stores are nontemporal (write-once data; keep x resident in
//    L2/L3 instead of letting the 268MB write stream evict it).
//  - XCD-pinned slab mapping (blockIdx % 8 == XCD, measured): every block
//    touching slab s=(b*C+c) lands on XCD s%8; the 16 horizontal blocks of a
//    slab are clustered within a 128-block dispatch window, so each 256KB
//    slab is read into the XCD's L2 once and re-served from L2.
//  - Vertical: ONE block per slab does BOTH up and down (t<128: down columns,
//    t>=128: up columns), sharing a single L2-resident copy of the slab.
__global__ __launch_bounds__(256) void irnn_fused(
    const float* __restrict__ x,
    const float* __restrict__ w_up,    const float* __restrict__ b_up,
    const float* __restrict__ w_right, const float* __restrict__ b_right,
    const float* __restrict__ w_down,  const float* __restrict__ b_down,
    const float* __restrict__ w_left,  const float* __restrict__ b_left,
    float* __restrict__ out)
{
    const int t   = threadIdx.x;
    const int blk = blockIdx.x;

    if (blk < 256) {
        // -------- vertical scans: block = slab, fused up+down --------
        const int  s   = blk;                  // slab (b*C + c); XCD = s%8
        const bool up  = t >= 128;
        const int  w2  = (t & 127) << 1;       // f2-column 0,2,..,254
        const int  c   = s & (NC - 1);
        const long base = (long)s * HW + w2;
        const float wc = up ? w_up[c] : w_down[c];
        const float bb = up ? b_up[c] : b_down[c];
        float* o = out + (up ? 0L : 2L) * PLANE;
        const long stp = up ? -(long)NW : (long)NW;
        long idx = up ? base + (long)(NH - 1) * NW : base;

        vf2 h = *(const vf2*)(x + idx);        // boundary row = raw input
        __builtin_nontemporal_store(h, (vf2*)(o + idx));
        for (int batch = 0; batch < 31; ++batch) {
            vf2 v[8];
            #pragma unroll
            for (int k = 0; k < 8; ++k)
                v[k] = *(const vf2*)(x + idx + (long)(k + 1) * stp);
            #pragma unroll
            for (int k = 0; k < 8; ++k) {
                h.x = fmaxf(wc * h.x + bb + v[k].x, 0.0f);
                h.y = fmaxf(wc * h.y + bb + v[k].y, 0.0f);
                __builtin_nontemporal_store(h, (vf2*)(o + idx + (long)(k + 1) * stp));
            }
            idx += 8L * stp;
        }
        vf2 v[7];
        #pragma unroll
        for (int k = 0; k < 7; ++k)
            v[k] = *(const vf2*)(x + idx + (long)(k + 1) * stp);
        #pragma unroll
        for (int k = 0; k < 7; ++k) {
            h.x = fmaxf(wc * h.x + bb + v[k].x, 0.0f);
            h.y = fmaxf(wc * h.y + bb + v[k].y, 0.0f);
            __builtin_nontemporal_store(h, (vf2*)(o + idx + (long)(k + 1) * stp));
        }
    } else {
        // -------- horizontal scans (fused right+left, wave per 4 rows) --------
        // Slab-clustered XCD-pinned decode: hb in [0,4096),
        //   s = (hb>>7)*8 + (hb&7)  -> blk%8 == s%8 (XCD pin)
        //   j = (hb&127)>>3         -> 16-row group; 16 blocks of slab s sit
        //                              within one 128-block dispatch window.
        const int hb = blk - 256;
        const int s  = ((hb >> 7) << 3) + (hb & 7);   // slab 0..255
        const int j  = (hb & 127) >> 3;               // 0..15
        const int lane = t & 63;
        const int c  = s & (NC - 1);
        const int h0 = j * 16 + (t >> 6) * 4;         // 4 rows per wave
        const float wr = w_right[c], br = b_right[c];
        const float wl = w_left[c],  bl = b_left[c];
        float* oR = out + 1L * PLANE;
        float* oL = out + 3L * PLANE;

        long rowb = (long)s * HW + (long)h0 * NW;
        vf4 v = *(const vf4*)(x + rowb + lane * 4);

        #pragma unroll
        for (int rr = 0; rr < 4; ++rr) {
            vf4 vn = v;
            if (rr < 3) vn = *(const vf4*)(x + rowb + NW + lane * 4); // prefetch

            float cc, mm, dd;
            vf4 r;

            // ---------------- RIGHT (scan toward +w) ----------------
            if (lane == 0) {
                float h = v.x;                      r.x = h;   // w=0: raw input
                h = fmaxf(wr * h + br + v.y, 0.0f); r.y = h;
                h = fmaxf(wr * h + br + v.z, 0.0f); r.z = h;
                h = fmaxf(wr * h + br + v.w, 0.0f); r.w = h;
                cc = h; mm = 0.0f; dd = h;          // constant function: m exactly 0
            } else {
                cc = 0.0f; mm = wr; dd = br + v.x;
                float a;
                a = br + v.y; cc = fmaxf(0.0f, wr * cc + a); dd = wr * dd + a; mm *= wr;
                a = br + v.z; cc = fmaxf(0.0f, wr * cc + a); dd = wr * dd + a; mm *= wr;
                a = br + v.w; cc = fmaxf(0.0f, wr * cc + a); dd = wr * dd + a; mm *= wr;
            }
            #pragma unroll
            for (int off = 1; off < 64; off <<= 1) {
                float pc = __shfl_up(cc, off, 64);
                float pm = __shfl_up(mm, off, 64);
                float pd = __shfl_up(dd, off, 64);
                if (lane >= off) {                  // mine AFTER partner
                    cc = fmaxf(cc, mm * pc + dd);
                    dd = mm * pd + dd;
                    mm = mm * pm;
                }
            }
            {
                float pc = __shfl_up(cc, 1, 64);
                float pd = __shfl_up(dd, 1, 64);
                if (lane > 0) {
                    float h = fmaxf(pc, pd);        // neighbor's m == 0 exactly
                    h = fmaxf(wr * h + br + v.x, 0.0f); r.x = h;
                    h = fmaxf(wr * h + br + v.y, 0.0f); r.y = h;
                    h = fmaxf(wr * h + br + v.z, 0.0f); r.z = h;
                    h = fmaxf(wr * h + br + v.w, 0.0f); r.w = h;
                }
            }
            __builtin_nontemporal_store(r, (vf4*)(oR + rowb + lane * 4));

            // ---------------- LEFT (scan toward -w) ----------------
            if (lane == 63) {
                float h = v.w;                      r.w = h;   // w=255: raw input
                h = fmaxf(wl * h + bl + v.z, 0.0f); r.z = h;
                h = fmaxf(wl * h + bl + v.y, 0.0f); r.y = h;
                h = fmaxf(wl * h + bl + v.x, 0.0f); r.x = h;
                cc = h; mm = 0.0f; dd = h;
            } else {
                cc = 0.0f; mm = wl; dd = bl + v.w;
                float a;
                a = bl + v.z; cc = fmaxf(0.0f, wl * cc + a); dd = wl * dd + a; mm *= wl;
                a = bl + v.y; cc = fmaxf(0.0f, wl * cc + a); dd = wl * dd + a; mm *= wl;
                a = bl + v.x; cc = fmaxf(0.0f, wl * cc + a); dd = wl * dd + a; mm *= wl;
            }
            #pragma unroll
            for (int off = 1; off < 64; off <<= 1) {
                float pc = __shfl_down(cc, off, 64);
                float pm = __shfl_down(mm, off, 64);
                float pd = __shfl_down(dd, off, 64);
                if (lane + off < 64) {
                    cc = fmaxf(cc, mm * pc + dd);
                    dd = mm * pd + dd;
                    mm = mm * pm;
                }
            }
            {
                float pc = __shfl_down(cc, 1, 64);
                float pd = __shfl_down(dd, 1, 64);
                if (lane < 63) {
                    float h = fmaxf(pc, pd);
                    h = fmaxf(wl * h + bl + v.w, 0.0f); r.w = h;
                    h = fmaxf(wl * h + bl + v.z, 0.0f); r.z = h;
                    h = fmaxf(wl * h + bl + v.y, 0.0f); r.y = h;
                    h = fmaxf(wl * h + bl + v.x, 0.0f); r.x = h;
                }
            }
            __builtin_nontemporal_store(r, (vf4*)(oL + rowb + lane * 4));

            rowb += NW;
            v = vn;
        }
    }
}

extern "C" void kernel_launch(void* const* d_in, const int* in_sizes, int n_in,
                              void* d_out, int out_size, void* d_ws, size_t ws_size,
                              hipStream_t stream) {
    const float* x       = (const float*)d_in[0];
    const float* w_up    = (const float*)d_in[1];
    const float* w_right = (const float*)d_in[2];
    const float* w_down  = (const float*)d_in[3];
    const float* w_left  = (const float*)d_in[4];
    const float* b_up    = (const float*)d_in[5];
    const float* b_right = (const float*)d_in[6];
    const float* b_down  = (const float*)d_in[7];
    const float* b_left  = (const float*)d_in[8];
    float* out = (float*)d_out;

    // [0,256): vertical, block = slab (up+down fused, XCD = s%8)
    // [256,4352): horizontal fused right+left, slab-clustered XCD-pinned
    dim3 grid(256 + 4096);
    irnn_fused<<<grid, 256, 0, stream>>>(
        x, w_up, b_up, w_right, b_right, w_down, b_down, w_left, b_left, out);
}